// Round 1
// baseline (324.136 us; speedup 1.0000x reference)
//
#include <hip/hip_runtime.h>
#include <hip/hip_bf16.h>

typedef __bf16 bf16x8 __attribute__((ext_vector_type(8)));
typedef __bf16 bf16x4 __attribute__((ext_vector_type(4)));
typedef float  f32x4  __attribute__((ext_vector_type(4)));

#define EPSV 1e-5f

// ---------------- prep: BN fold constants ----------------
__global__ void prep_consts(
    const float* __restrict__ b1, const float* __restrict__ g1, const float* __restrict__ be1,
    const float* __restrict__ m1, const float* __restrict__ v1,
    const float* __restrict__ b2, const float* __restrict__ g2, const float* __restrict__ be2,
    const float* __restrict__ m2, const float* __restrict__ v2,
    const float* __restrict__ b3, const float* __restrict__ g3, const float* __restrict__ be3,
    const float* __restrict__ m3, const float* __restrict__ v3,
    float* __restrict__ sc1, float* __restrict__ sh1,
    float* __restrict__ sc2, float* __restrict__ sh2,
    float* __restrict__ sc3, float* __restrict__ sh3) {
  int t = threadIdx.x;
  if (t < 512) { float s = g1[t] * rsqrtf(v1[t] + EPSV); sc1[t] = s; sh1[t] = be1[t] + (b1[t] - m1[t]) * s; }
  if (t < 256) { float s = g2[t] * rsqrtf(v2[t] + EPSV); sc2[t] = s; sh2[t] = be2[t] + (b2[t] - m2[t]) * s; }
  if (t < 64)  { float s = g3[t] * rsqrtf(v3[t] + EPSV); sc3[t] = s; sh3[t] = be3[t] + (b3[t] - m3[t]) * s; }
}

// ---------------- prep: W2/W3 -> bf16 ----------------
__global__ void prep_convert(const float* __restrict__ W2, const float* __restrict__ W3,
                             __bf16* __restrict__ W2bf, __bf16* __restrict__ W3bf) {
  int idx = blockIdx.x * 256 + threadIdx.x;
  if (idx < 256 * 512) W2bf[idx] = (__bf16)W2[idx];
  if (idx < 64 * 256)  W3bf[idx] = (__bf16)W3[idx];
}

// ---------------- prep: layer-1 factorization ----------------
// A'[b][o][i] = (sum_c W1[o][c]     * x[b][c][i]) * sc1[o] + sh1[o]
// B'[b][o][j] = (sum_c W1[o][128+c] * x[b][c][j]) * sc1[o]
// h1[o][pt(i,j)] = relu(A'[o][i] + B'[o][j])   (generated in main kernel)
__global__ void prep_ab(const float* __restrict__ x, const float* __restrict__ W1,
                        const float* __restrict__ sc1, const float* __restrict__ sh1,
                        float* __restrict__ Ap, float* __restrict__ Bp) {
  int b  = blockIdx.x >> 7;
  int og = blockIdx.x & 127;   // group of 4 output channels
  int i  = threadIdx.x;        // point index, coalesced
  float accA[4] = {0.f, 0.f, 0.f, 0.f};
  float accB[4] = {0.f, 0.f, 0.f, 0.f};
  const float* xb  = x  + (size_t)b * 128 * 256 + i;
  const float* w1r = W1 + (size_t)og * 4 * 256;   // uniform per block -> s_loads
  for (int c = 0; c < 128; ++c) {
    float xa = xb[c * 256];
    #pragma unroll
    for (int oo = 0; oo < 4; ++oo) {
      accA[oo] = fmaf(w1r[oo * 256 + c],       xa, accA[oo]);
      accB[oo] = fmaf(w1r[oo * 256 + 128 + c], xa, accB[oo]);
    }
  }
  #pragma unroll
  for (int oo = 0; oo < 4; ++oo) {
    int o = og * 4 + oo;
    Ap[((size_t)b * 512 + o) * 256 + i] = accA[oo] * sc1[o] + sh1[o];
    Bp[((size_t)b * 512 + o) * 256 + i] = accB[oo] * sc1[o];
  }
}

// ---------------- main fused kernel ----------------
// grid: 8192 blocks = b(8) x it(32) x jt(32); block = 256 thr = 4 waves.
// Tile = 64 points (8 i x 8 j). Wave w owns output channels [64w, 64w+64) of L2.
struct alignas(16) SmemL2 {
  float sA[8][520];         // A' tile, [ii][k] — 520 pad: banks (8*gi+k0)%32 spread
  float sB[8][520];         // B' tile, [jj][k]
  __bf16 h1[64][40];        // h1 chunk for one k-step: [pt][kk], +8 pad (2-way max)
};
struct alignas(16) SmemL34 {
  __bf16 h2[64][264];       // [pt][ch2], +8 pad
  float  h3[64][68];        // [pt][ch3], +4 pad
  float  part[256];
};
union alignas(16) Smem { SmemL2 s2; SmemL34 s3; };  // 52224 B -> 3 blocks/CU

__global__ __launch_bounds__(256, 3) void edge_main(
    const float* __restrict__ Ap, const float* __restrict__ Bp,
    const __bf16* __restrict__ W2bf, const __bf16* __restrict__ W3bf,
    const float* __restrict__ sc2, const float* __restrict__ sh2,
    const float* __restrict__ sc3, const float* __restrict__ sh3,
    const float* __restrict__ W4, const float* __restrict__ b4,
    float* __restrict__ out) {
  __shared__ Smem u;
  const int blk = blockIdx.x;
  const int b  = blk >> 10;
  const int it = (blk >> 5) & 31;
  const int jt = blk & 31;
  const int i0 = it * 8, j0 = jt * 8;

  const int t    = threadIdx.x;
  const int w    = t >> 6;
  const int lane = t & 63;
  const int llo  = lane & 15;   // MFMA row/col within fragment
  const int lhi  = lane >> 4;   // MFMA k-group

  // ---- stage A'/B' (512 x 8 each) into LDS, transposed to [ii][k] ----
  #pragma unroll
  for (int rr = 0; rr < 2; ++rr) {
    int o = t + rr * 256;
    const float4* As = (const float4*)(Ap + ((size_t)b * 512 + o) * 256 + i0);
    const float4* Bs = (const float4*)(Bp + ((size_t)b * 512 + o) * 256 + j0);
    float4 a0 = As[0], a1 = As[1];
    float4 b0 = Bs[0], b1 = Bs[1];
    u.s2.sA[0][o] = a0.x; u.s2.sA[1][o] = a0.y; u.s2.sA[2][o] = a0.z; u.s2.sA[3][o] = a0.w;
    u.s2.sA[4][o] = a1.x; u.s2.sA[5][o] = a1.y; u.s2.sA[6][o] = a1.z; u.s2.sA[7][o] = a1.w;
    u.s2.sB[0][o] = b0.x; u.s2.sB[1][o] = b0.y; u.s2.sB[2][o] = b0.z; u.s2.sB[3][o] = b0.w;
    u.s2.sB[4][o] = b1.x; u.s2.sB[5][o] = b1.y; u.s2.sB[6][o] = b1.z; u.s2.sB[7][o] = b1.w;
  }

  const f32x4 vzero = {0.f, 0.f, 0.f, 0.f};
  f32x4 acc[4][4];
  #pragma unroll
  for (int mt = 0; mt < 4; ++mt)
    #pragma unroll
    for (int nt = 0; nt < 4; ++nt) acc[mt][nt] = vzero;

  const int mbase = w * 64;
  const int pt_g  = t >> 2;          // 0..63: point this thread generates h1 for
  const int kks   = (t & 3) * 8;     // 8 k-values within the 32-k chunk
  const int gi    = pt_g >> 3;
  const int gj    = pt_g & 7;

  const __bf16* w2p = W2bf + (size_t)(mbase + llo) * 512 + lhi * 8;

  // ---- layer 2 K-loop: 16 steps of K=32 ----
  for (int ks = 0; ks < 16; ++ks) {
    bf16x8 af[4];                               // W2 frags (L2-resident, no LDS)
    #pragma unroll
    for (int mt = 0; mt < 4; ++mt)
      af[mt] = *(const bf16x8*)(w2p + (size_t)mt * 16 * 512 + ks * 32);

    __syncthreads();                            // WAR on h1 vs prev MFMA reads
    {
      int k0 = ks * 32 + kks;
      float4 av0 = *(const float4*)&u.s2.sA[gi][k0];
      float4 av1 = *(const float4*)&u.s2.sA[gi][k0 + 4];
      float4 bv0 = *(const float4*)&u.s2.sB[gj][k0];
      float4 bv1 = *(const float4*)&u.s2.sB[gj][k0 + 4];
      bf16x8 hv;
      hv[0] = (__bf16)fmaxf(av0.x + bv0.x, 0.f);
      hv[1] = (__bf16)fmaxf(av0.y + bv0.y, 0.f);
      hv[2] = (__bf16)fmaxf(av0.z + bv0.z, 0.f);
      hv[3] = (__bf16)fmaxf(av0.w + bv0.w, 0.f);
      hv[4] = (__bf16)fmaxf(av1.x + bv1.x, 0.f);
      hv[5] = (__bf16)fmaxf(av1.y + bv1.y, 0.f);
      hv[6] = (__bf16)fmaxf(av1.z + bv1.z, 0.f);
      hv[7] = (__bf16)fmaxf(av1.w + bv1.w, 0.f);
      *(bf16x8*)&u.s2.h1[pt_g][kks] = hv;       // 16B store, 16B-aligned
    }
    __syncthreads();

    bf16x8 bfr[4];
    #pragma unroll
    for (int nt = 0; nt < 4; ++nt)
      bfr[nt] = *(const bf16x8*)&u.s2.h1[nt * 16 + llo][lhi * 8];

    #pragma unroll
    for (int mt = 0; mt < 4; ++mt)
      #pragma unroll
      for (int nt = 0; nt < 4; ++nt)
        acc[mt][nt] = __builtin_amdgcn_mfma_f32_16x16x32_bf16(af[mt], bfr[nt], acc[mt][nt], 0, 0, 0);
  }

  __syncthreads();   // union phase switch: h2 aliases sA/sB/h1

  // ---- BN2 + ReLU -> h2 (bf16 in LDS) ----
  #pragma unroll
  for (int mt = 0; mt < 4; ++mt) {
    int ch = mbase + mt * 16 + lhi * 4;
    float4 s = *(const float4*)(sc2 + ch);
    float4 h = *(const float4*)(sh2 + ch);
    #pragma unroll
    for (int nt = 0; nt < 4; ++nt) {
      int pt = nt * 16 + llo;
      bf16x4 hb;
      hb[0] = (__bf16)fmaxf(fmaf(acc[mt][nt][0], s.x, h.x), 0.f);
      hb[1] = (__bf16)fmaxf(fmaf(acc[mt][nt][1], s.y, h.y), 0.f);
      hb[2] = (__bf16)fmaxf(fmaf(acc[mt][nt][2], s.z, h.z), 0.f);
      hb[3] = (__bf16)fmaxf(fmaf(acc[mt][nt][3], s.w, h.w), 0.f);
      *(bf16x4*)&u.s3.h2[pt][ch] = hb;          // 8B store, 8B-aligned
    }
  }
  __syncthreads();

  // ---- layer 3: out3[64][64] = W3[64x256] @ h2[256x64]; wave w -> rows 16w.. ----
  f32x4 acc3[4];
  #pragma unroll
  for (int nt = 0; nt < 4; ++nt) acc3[nt] = vzero;
  const __bf16* w3p = W3bf + (size_t)(w * 16 + llo) * 256 + lhi * 8;
  #pragma unroll
  for (int ks = 0; ks < 8; ++ks) {
    bf16x8 a3 = *(const bf16x8*)(w3p + ks * 32);
    #pragma unroll
    for (int nt = 0; nt < 4; ++nt) {
      bf16x8 b3 = *(const bf16x8*)&u.s3.h2[nt * 16 + llo][ks * 32 + lhi * 8];
      acc3[nt] = __builtin_amdgcn_mfma_f32_16x16x32_bf16(a3, b3, acc3[nt], 0, 0, 0);
    }
  }

  // ---- BN3 + ReLU -> h3 (f32 in LDS) ----
  {
    int ch3 = w * 16 + lhi * 4;
    float4 s = *(const float4*)(sc3 + ch3);
    float4 h = *(const float4*)(sh3 + ch3);
    #pragma unroll
    for (int nt = 0; nt < 4; ++nt) {
      int pt = nt * 16 + llo;
      float4 hv;
      hv.x = fmaxf(fmaf(acc3[nt][0], s.x, h.x), 0.f);
      hv.y = fmaxf(fmaf(acc3[nt][1], s.y, h.y), 0.f);
      hv.z = fmaxf(fmaf(acc3[nt][2], s.z, h.z), 0.f);
      hv.w = fmaxf(fmaf(acc3[nt][3], s.w, h.w), 0.f);
      *(float4*)&u.s3.h3[pt][ch3] = hv;         // 16B store, 16B-aligned
    }
  }
  __syncthreads();

  // ---- layer 4: dot(W4, h3) + b4, sigmoid ----
  {
    int pt = t & 63;
    int q  = t >> 6;          // wave-uniform quarter -> scalar W4 loads
    float sum = 0.f;
    #pragma unroll
    for (int e = 0; e < 4; ++e) {
      float4 hv = *(const float4*)&u.s3.h3[pt][q * 16 + e * 4];
      float4 wv = *(const float4*)(W4 + q * 16 + e * 4);
      sum += hv.x * wv.x + hv.y * wv.y + hv.z * wv.z + hv.w * wv.w;
    }
    u.s3.part[t] = sum;
  }
  __syncthreads();
  if (t < 64) {
    float tot = u.s3.part[t] + u.s3.part[t + 64] + u.s3.part[t + 128] + u.s3.part[t + 192] + b4[0];
    float sg = 1.f / (1.f + __expf(-tot));
    out[(size_t)b * 65536 + (size_t)(i0 + (t >> 3)) * 256 + (j0 + (t & 7))] = sg;
  }
}

// ---------------- launcher ----------------
extern "C" void kernel_launch(void* const* d_in, const int* in_sizes, int n_in,
                              void* d_out, int out_size, void* d_ws, size_t ws_size,
                              hipStream_t stream) {
  const float* x   = (const float*)d_in[0];
  const float* W1  = (const float*)d_in[1];
  const float* b1  = (const float*)d_in[2];
  const float* g1  = (const float*)d_in[3];
  const float* be1 = (const float*)d_in[4];
  const float* m1  = (const float*)d_in[5];
  const float* v1  = (const float*)d_in[6];
  const float* W2  = (const float*)d_in[7];
  const float* b2  = (const float*)d_in[8];
  const float* g2  = (const float*)d_in[9];
  const float* be2 = (const float*)d_in[10];
  const float* m2  = (const float*)d_in[11];
  const float* v2  = (const float*)d_in[12];
  const float* W3  = (const float*)d_in[13];
  const float* b3  = (const float*)d_in[14];
  const float* g3  = (const float*)d_in[15];
  const float* be3 = (const float*)d_in[16];
  const float* m3  = (const float*)d_in[17];
  const float* v3  = (const float*)d_in[18];
  const float* W4  = (const float*)d_in[19];
  const float* b4  = (const float*)d_in[20];

  // workspace layout (8.7 MB total)
  float* Ap  = (float*)d_ws;             // 8*512*256 = 1048576 f32
  float* Bp  = Ap + 1048576;             // 1048576 f32
  float* sc1 = Bp + 1048576;             // 512
  float* sh1 = sc1 + 512;                // 512
  float* sc2 = sh1 + 512;                // 256
  float* sh2 = sc2 + 256;                // 256
  float* sc3 = sh2 + 256;                // 64
  float* sh3 = sc3 + 64;                 // 64
  __bf16* W2bf = (__bf16*)(sh3 + 64);    // 131072 bf16 (16B-aligned offset)
  __bf16* W3bf = W2bf + 131072;          // 16384 bf16

  prep_consts<<<1, 512, 0, stream>>>(b1, g1, be1, m1, v1, b2, g2, be2, m2, v2,
                                     b3, g3, be3, m3, v3, sc1, sh1, sc2, sh2, sc3, sh3);
  prep_convert<<<512, 256, 0, stream>>>(W2, W3, W2bf, W3bf);
  prep_ab<<<1024, 256, 0, stream>>>(x, W1, sc1, sh1, Ap, Bp);
  edge_main<<<8192, 256, 0, stream>>>(Ap, Bp, W2bf, W3bf, sc2, sh2, sc3, sh3, W4, b4, (float*)d_out);
}

// Round 2
// 301.997 us; speedup vs baseline: 1.0733x; 1.0733x over previous
//
#include <hip/hip_runtime.h>
#include <hip/hip_bf16.h>

typedef __bf16 bf16x8 __attribute__((ext_vector_type(8)));
typedef __bf16 bf16x4 __attribute__((ext_vector_type(4)));
typedef float  f32x4  __attribute__((ext_vector_type(4)));

#define EPSV 1e-5f

// ---------------- prep: BN fold constants ----------------
__global__ void prep_consts(
    const float* __restrict__ b1, const float* __restrict__ g1, const float* __restrict__ be1,
    const float* __restrict__ m1, const float* __restrict__ v1,
    const float* __restrict__ b2, const float* __restrict__ g2, const float* __restrict__ be2,
    const float* __restrict__ m2, const float* __restrict__ v2,
    const float* __restrict__ b3, const float* __restrict__ g3, const float* __restrict__ be3,
    const float* __restrict__ m3, const float* __restrict__ v3,
    float* __restrict__ sc1, float* __restrict__ sh1,
    float* __restrict__ sc2, float* __restrict__ sh2,
    float* __restrict__ sc3, float* __restrict__ sh3) {
  int t = threadIdx.x;
  if (t < 512) { float s = g1[t] * rsqrtf(v1[t] + EPSV); sc1[t] = s; sh1[t] = be1[t] + (b1[t] - m1[t]) * s; }
  if (t < 256) { float s = g2[t] * rsqrtf(v2[t] + EPSV); sc2[t] = s; sh2[t] = be2[t] + (b2[t] - m2[t]) * s; }
  if (t < 64)  { float s = g3[t] * rsqrtf(v3[t] + EPSV); sc3[t] = s; sh3[t] = be3[t] + (b3[t] - m3[t]) * s; }
}

// ---------------- prep: W2/W3 -> bf16 ----------------
__global__ void prep_convert(const float* __restrict__ W2, const float* __restrict__ W3,
                             __bf16* __restrict__ W2bf, __bf16* __restrict__ W3bf) {
  int idx = blockIdx.x * 256 + threadIdx.x;
  if (idx < 256 * 512) W2bf[idx] = (__bf16)W2[idx];
  if (idx < 64 * 256)  W3bf[idx] = (__bf16)W3[idx];
}

// ---------------- prep: layer-1 factorization ----------------
// Layout: Ap[b][i][o] (i-major, o contiguous) so edge_main staging is coalesced.
// A'[b][i][o] = (sum_c W1[o][c]     * x[b][c][i]) * sc1[o] + sh1[o]
// B'[b][j][o] = (sum_c W1[o][128+c] * x[b][c][j]) * sc1[o]
__global__ void prep_ab(const float* __restrict__ x, const float* __restrict__ W1,
                        const float* __restrict__ sc1, const float* __restrict__ sh1,
                        float* __restrict__ Ap, float* __restrict__ Bp) {
  int b  = blockIdx.x >> 7;
  int og = blockIdx.x & 127;   // group of 4 output channels
  int i  = threadIdx.x;        // point index, coalesced on x
  float accA[4] = {0.f, 0.f, 0.f, 0.f};
  float accB[4] = {0.f, 0.f, 0.f, 0.f};
  const float* xb  = x  + (size_t)b * 128 * 256 + i;
  const float* w1r = W1 + (size_t)og * 4 * 256;   // uniform per block -> s_loads
  for (int c = 0; c < 128; ++c) {
    float xa = xb[c * 256];
    #pragma unroll
    for (int oo = 0; oo < 4; ++oo) {
      accA[oo] = fmaf(w1r[oo * 256 + c],       xa, accA[oo]);
      accB[oo] = fmaf(w1r[oo * 256 + 128 + c], xa, accB[oo]);
    }
  }
  float4 oa, ob;
  {
    int o0 = og * 4;
    float4 s = *(const float4*)(sc1 + o0);
    float4 h = *(const float4*)(sh1 + o0);
    oa.x = accA[0] * s.x + h.x; oa.y = accA[1] * s.y + h.y;
    oa.z = accA[2] * s.z + h.z; oa.w = accA[3] * s.w + h.w;
    ob.x = accB[0] * s.x; ob.y = accB[1] * s.y;
    ob.z = accB[2] * s.z; ob.w = accB[3] * s.w;
  }
  size_t base = ((size_t)(b * 256 + i) << 9) + og * 4;
  *(float4*)(Ap + base) = oa;
  *(float4*)(Bp + base) = ob;
}

// ---------------- main fused kernel ----------------
// grid: 8192 blocks = b(8) x it(32) x jt(32); block = 256 thr = 4 waves.
// Tile = 64 points (8 i x 8 j). Wave w owns output channels [64w, 64w+64) of L2.
// k-loop is BARRIER-FREE: h1 fragments are generated in registers from
// LDS-broadcast A'/B' slices (stride 516 == 4 mod 32 banks: A-reads 1cy, B-reads 4cy floor).
struct alignas(16) Smem {
  union {
    struct { float sA[8][516]; float sB[8][516]; } s2;   // 33024 B, [row][k]
    __bf16 h2[64][264];                                  // 33792 B, [pt][ch]
  } u;
  float part[4][64];                                     // 1024 B
};  // 34816 B -> 4 blocks/CU by LDS

__global__ __launch_bounds__(256, 3) void edge_main(
    const float* __restrict__ Ap, const float* __restrict__ Bp,
    const __bf16* __restrict__ W2bf, const __bf16* __restrict__ W3bf,
    const float* __restrict__ sc2, const float* __restrict__ sh2,
    const float* __restrict__ sc3, const float* __restrict__ sh3,
    const float* __restrict__ W4, const float* __restrict__ b4,
    float* __restrict__ out) {
  __shared__ Smem sm;
  const int blk = blockIdx.x;
  const int b  = blk >> 10;
  const int it = (blk >> 5) & 31;
  const int jt = blk & 31;
  const int i0 = it * 8, j0 = jt * 8;

  const int t    = threadIdx.x;
  const int w    = t >> 6;
  const int lane = t & 63;
  const int llo  = lane & 15;   // MFMA row/col within fragment
  const int lhi  = lane >> 4;   // MFMA k-group

  // ---- stage A'/B' tiles into LDS [row][k], fully coalesced global reads ----
  {
    int ii = t >> 5;               // 0..7
    int cb = (t & 31) * 4;         // 0..124 (x4 floats)
    const float* aRowG = Ap + ((size_t)(b * 256 + i0 + ii) << 9);
    const float* bRowG = Bp + ((size_t)(b * 256 + j0 + ii) << 9);
    #pragma unroll
    for (int seg = 0; seg < 4; ++seg) {
      float4 av = *(const float4*)(aRowG + cb + seg * 128);
      float4 bv = *(const float4*)(bRowG + cb + seg * 128);
      *(float4*)&sm.u.s2.sA[ii][cb + seg * 128] = av;
      *(float4*)&sm.u.s2.sB[ii][cb + seg * 128] = bv;
    }
  }

  const f32x4 vzero = {0.f, 0.f, 0.f, 0.f};
  f32x4 acc[4][4];
  #pragma unroll
  for (int mt = 0; mt < 4; ++mt)
    #pragma unroll
    for (int nt = 0; nt < 4; ++nt) acc[mt][nt] = vzero;

  const int mbase = w * 64;
  const int gj    = llo & 7;     // j-row of this lane's point column
  const int giOff = llo >> 3;    // i-row parity within nt pair
  const __bf16* w2p = W2bf + (size_t)(mbase + llo) * 512 + lhi * 8;

  __syncthreads();   // staging complete; sA/sB read-only from here

  // ---- layer 2 K-loop: 16 steps of K=32, NO barriers ----
  for (int ks = 0; ks < 16; ++ks) {
    const int k0 = ks * 32 + lhi * 8;

    bf16x8 af[4];                               // W2 frags (L2-resident)
    #pragma unroll
    for (int mt = 0; mt < 4; ++mt)
      af[mt] = *(const bf16x8*)(w2p + (size_t)mt * 16 * 512 + ks * 32);

    float4 b0 = *(const float4*)&sm.u.s2.sB[gj][k0];
    float4 b1 = *(const float4*)&sm.u.s2.sB[gj][k0 + 4];

    bf16x8 bfr[4];
    #pragma unroll
    for (int nt = 0; nt < 4; ++nt) {
      const float* ar = sm.u.s2.sA[nt * 2 + giOff];
      float4 a0 = *(const float4*)&ar[k0];
      float4 a1 = *(const float4*)&ar[k0 + 4];
      bf16x8 hv;
      hv[0] = (__bf16)fmaxf(a0.x + b0.x, 0.f);
      hv[1] = (__bf16)fmaxf(a0.y + b0.y, 0.f);
      hv[2] = (__bf16)fmaxf(a0.z + b0.z, 0.f);
      hv[3] = (__bf16)fmaxf(a0.w + b0.w, 0.f);
      hv[4] = (__bf16)fmaxf(a1.x + b1.x, 0.f);
      hv[5] = (__bf16)fmaxf(a1.y + b1.y, 0.f);
      hv[6] = (__bf16)fmaxf(a1.z + b1.z, 0.f);
      hv[7] = (__bf16)fmaxf(a1.w + b1.w, 0.f);
      bfr[nt] = hv;
    }

    #pragma unroll
    for (int mt = 0; mt < 4; ++mt)
      #pragma unroll
      for (int nt = 0; nt < 4; ++nt)
        acc[mt][nt] = __builtin_amdgcn_mfma_f32_16x16x32_bf16(af[mt], bfr[nt], acc[mt][nt], 0, 0, 0);
  }

  __syncthreads();   // all waves done reading sA/sB; union phase switch to h2

  // ---- BN2 + ReLU -> h2 (bf16 in LDS) ----
  #pragma unroll
  for (int mt = 0; mt < 4; ++mt) {
    int ch = mbase + mt * 16 + lhi * 4;
    float4 s = *(const float4*)(sc2 + ch);
    float4 h = *(const float4*)(sh2 + ch);
    #pragma unroll
    for (int nt = 0; nt < 4; ++nt) {
      int pt = nt * 16 + llo;
      bf16x4 hb;
      hb[0] = (__bf16)fmaxf(fmaf(acc[mt][nt][0], s.x, h.x), 0.f);
      hb[1] = (__bf16)fmaxf(fmaf(acc[mt][nt][1], s.y, h.y), 0.f);
      hb[2] = (__bf16)fmaxf(fmaf(acc[mt][nt][2], s.z, h.z), 0.f);
      hb[3] = (__bf16)fmaxf(fmaf(acc[mt][nt][3], s.w, h.w), 0.f);
      *(bf16x4*)&sm.u.h2[pt][ch] = hb;          // 8B store, 8B-aligned (528B rows)
    }
  }
  __syncthreads();

  // ---- layer 3: wave w -> output channels [16w,16w+16) ----
  f32x4 acc3[4];
  #pragma unroll
  for (int nt = 0; nt < 4; ++nt) acc3[nt] = vzero;
  const __bf16* w3p = W3bf + (size_t)(w * 16 + llo) * 256 + lhi * 8;
  #pragma unroll
  for (int ks = 0; ks < 8; ++ks) {
    bf16x8 a3 = *(const bf16x8*)(w3p + ks * 32);
    #pragma unroll
    for (int nt = 0; nt < 4; ++nt) {
      bf16x8 b3 = *(const bf16x8*)&sm.u.h2[nt * 16 + llo][ks * 32 + lhi * 8];
      acc3[nt] = __builtin_amdgcn_mfma_f32_16x16x32_bf16(a3, b3, acc3[nt], 0, 0, 0);
    }
  }

  // ---- BN3 + ReLU + W4 dot folded in registers; cross-lane shfl reduce ----
  {
    int ch3 = w * 16 + lhi * 4;
    float4 s  = *(const float4*)(sc3 + ch3);
    float4 h  = *(const float4*)(sh3 + ch3);
    float4 wv = *(const float4*)(W4 + ch3);
    #pragma unroll
    for (int nt = 0; nt < 4; ++nt) {
      float p = fmaxf(fmaf(acc3[nt][0], s.x, h.x), 0.f) * wv.x
              + fmaxf(fmaf(acc3[nt][1], s.y, h.y), 0.f) * wv.y
              + fmaxf(fmaf(acc3[nt][2], s.z, h.z), 0.f) * wv.z
              + fmaxf(fmaf(acc3[nt][3], s.w, h.w), 0.f) * wv.w;
      p += __shfl_xor(p, 16);
      p += __shfl_xor(p, 32);
      if (lane < 16) sm.part[w][nt * 16 + llo] = p;   // lhi==0 lanes
    }
  }
  __syncthreads();

  // ---- cross-wave sum + sigmoid + store ----
  if (t < 64) {
    float tot = sm.part[0][t] + sm.part[1][t] + sm.part[2][t] + sm.part[3][t] + b4[0];
    float sg = 1.f / (1.f + __expf(-tot));
    out[(size_t)b * 65536 + (size_t)(i0 + (t >> 3)) * 256 + (j0 + (t & 7))] = sg;
  }
}

// ---------------- launcher ----------------
extern "C" void kernel_launch(void* const* d_in, const int* in_sizes, int n_in,
                              void* d_out, int out_size, void* d_ws, size_t ws_size,
                              hipStream_t stream) {
  const float* x   = (const float*)d_in[0];
  const float* W1  = (const float*)d_in[1];
  const float* b1  = (const float*)d_in[2];
  const float* g1  = (const float*)d_in[3];
  const float* be1 = (const float*)d_in[4];
  const float* m1  = (const float*)d_in[5];
  const float* v1  = (const float*)d_in[6];
  const float* W2  = (const float*)d_in[7];
  const float* b2  = (const float*)d_in[8];
  const float* g2  = (const float*)d_in[9];
  const float* be2 = (const float*)d_in[10];
  const float* m2  = (const float*)d_in[11];
  const float* v2  = (const float*)d_in[12];
  const float* W3  = (const float*)d_in[13];
  const float* b3  = (const float*)d_in[14];
  const float* g3  = (const float*)d_in[15];
  const float* be3 = (const float*)d_in[16];
  const float* m3  = (const float*)d_in[17];
  const float* v3  = (const float*)d_in[18];
  const float* W4  = (const float*)d_in[19];
  const float* b4  = (const float*)d_in[20];

  // workspace layout (8.7 MB total)
  float* Ap  = (float*)d_ws;             // 8*256*512 = 1048576 f32, [b][i][o]
  float* Bp  = Ap + 1048576;             // 1048576 f32, [b][j][o]
  float* sc1 = Bp + 1048576;             // 512
  float* sh1 = sc1 + 512;                // 512
  float* sc2 = sh1 + 512;                // 256
  float* sh2 = sc2 + 256;                // 256
  float* sc3 = sh2 + 256;                // 64
  float* sh3 = sc3 + 64;                 // 64
  __bf16* W2bf = (__bf16*)(sh3 + 64);    // 131072 bf16 (16B-aligned offset)
  __bf16* W3bf = W2bf + 131072;          // 16384 bf16

  prep_consts<<<1, 512, 0, stream>>>(b1, g1, be1, m1, v1, b2, g2, be2, m2, v2,
                                     b3, g3, be3, m3, v3, sc1, sh1, sc2, sh2, sc3, sh3);
  prep_convert<<<512, 256, 0, stream>>>(W2, W3, W2bf, W3bf);
  prep_ab<<<1024, 256, 0, stream>>>(x, W1, sc1, sh1, Ap, Bp);
  edge_main<<<8192, 256, 0, stream>>>(Ap, Bp, W2bf, W3bf, sc2, sh2, sc3, sh3, W4, b4, (float*)d_out);
}

// Round 3
// 298.139 us; speedup vs baseline: 1.0872x; 1.0129x over previous
//
#include <hip/hip_runtime.h>
#include <hip/hip_bf16.h>
#include <hip/hip_fp16.h>

typedef _Float16 f16x8 __attribute__((ext_vector_type(8)));
typedef _Float16 f16x4 __attribute__((ext_vector_type(4)));
typedef float    f32x4 __attribute__((ext_vector_type(4)));

#define EPSV 1e-5f

// ---------------- prep: BN fold constants ----------------
__global__ void prep_consts(
    const float* __restrict__ b1, const float* __restrict__ g1, const float* __restrict__ be1,
    const float* __restrict__ m1, const float* __restrict__ v1,
    const float* __restrict__ b2, const float* __restrict__ g2, const float* __restrict__ be2,
    const float* __restrict__ m2, const float* __restrict__ v2,
    const float* __restrict__ b3, const float* __restrict__ g3, const float* __restrict__ be3,
    const float* __restrict__ m3, const float* __restrict__ v3,
    float* __restrict__ sc1, float* __restrict__ sh1,
    float* __restrict__ sc2, float* __restrict__ sh2,
    float* __restrict__ sc3, float* __restrict__ sh3) {
  int t = threadIdx.x;
  if (t < 512) { float s = g1[t] * rsqrtf(v1[t] + EPSV); sc1[t] = s; sh1[t] = be1[t] + (b1[t] - m1[t]) * s; }
  if (t < 256) { float s = g2[t] * rsqrtf(v2[t] + EPSV); sc2[t] = s; sh2[t] = be2[t] + (b2[t] - m2[t]) * s; }
  if (t < 64)  { float s = g3[t] * rsqrtf(v3[t] + EPSV); sc3[t] = s; sh3[t] = be3[t] + (b3[t] - m3[t]) * s; }
}

// ---------------- prep: W2/W3 -> fp16 ----------------
__global__ void prep_convert(const float* __restrict__ W2, const float* __restrict__ W3,
                             _Float16* __restrict__ W2h, _Float16* __restrict__ W3h) {
  int idx = blockIdx.x * 256 + threadIdx.x;
  if (idx < 256 * 512) W2h[idx] = (_Float16)W2[idx];
  if (idx < 64 * 256)  W3h[idx] = (_Float16)W3[idx];
}

// ---------------- prep: layer-1 factorization ----------------
// Layout: Ap[b][i][o] (o contiguous, f16) so edge_main staging is coalesced.
// A'[b][i][o] = (sum_c W1[o][c]     * x[b][c][i]) * sc1[o] + sh1[o]
// B'[b][j][o] = (sum_c W1[o][128+c] * x[b][c][j]) * sc1[o]
__global__ void prep_ab(const float* __restrict__ x, const float* __restrict__ W1,
                        const float* __restrict__ sc1, const float* __restrict__ sh1,
                        _Float16* __restrict__ Ap, _Float16* __restrict__ Bp) {
  int b  = blockIdx.x >> 7;
  int og = blockIdx.x & 127;   // group of 4 output channels
  int i  = threadIdx.x;        // point index, coalesced on x
  float accA[4] = {0.f, 0.f, 0.f, 0.f};
  float accB[4] = {0.f, 0.f, 0.f, 0.f};
  const float* xb  = x  + (size_t)b * 128 * 256 + i;
  const float* w1r = W1 + (size_t)og * 4 * 256;   // uniform per block -> s_loads
  for (int c = 0; c < 128; ++c) {
    float xa = xb[c * 256];
    #pragma unroll
    for (int oo = 0; oo < 4; ++oo) {
      accA[oo] = fmaf(w1r[oo * 256 + c],       xa, accA[oo]);
      accB[oo] = fmaf(w1r[oo * 256 + 128 + c], xa, accB[oo]);
    }
  }
  f16x4 oa, ob;
  {
    int o0 = og * 4;
    float4 s = *(const float4*)(sc1 + o0);
    float4 h = *(const float4*)(sh1 + o0);
    oa[0] = (_Float16)(accA[0] * s.x + h.x); oa[1] = (_Float16)(accA[1] * s.y + h.y);
    oa[2] = (_Float16)(accA[2] * s.z + h.z); oa[3] = (_Float16)(accA[3] * s.w + h.w);
    ob[0] = (_Float16)(accB[0] * s.x); ob[1] = (_Float16)(accB[1] * s.y);
    ob[2] = (_Float16)(accB[2] * s.z); ob[3] = (_Float16)(accB[3] * s.w);
  }
  size_t base = ((size_t)(b * 256 + i) << 9) + og * 4;
  *(f16x4*)(Ap + base) = oa;
  *(f16x4*)(Bp + base) = ob;
}

// ---------------- main fused kernel ----------------
// grid: 8192 blocks = b(8) x it(32) x jt(32); block = 256 thr = 4 waves.
// Tile = 64 points (8 i x 8 j). Wave w owns output channels [64w, 64w+64) of L2.
// k-loop: barrier-free, fp16 datapath (v_pk_add/max_f16 h1-gen), af register
// double-buffer to hide W2 L2 latency under the MFMA stretch.
// sA/sB row stride 544 f16 = 272 words == 16 mod 32: A-reads conflict-free,
// B-reads at the 4-sweep (512B/128B) minimum.
struct alignas(16) Smem {
  union {
    struct { _Float16 sA[8][544]; _Float16 sB[8][544]; } s2;  // 17408 B
    _Float16 h2[64][264];                                     // 33792 B
  } u;
  float part[4][64];                                          // 1024 B
};  // 34816 B

__global__ __launch_bounds__(256, 4) void edge_main(
    const _Float16* __restrict__ Ap, const _Float16* __restrict__ Bp,
    const _Float16* __restrict__ W2h, const _Float16* __restrict__ W3h,
    const float* __restrict__ sc2, const float* __restrict__ sh2,
    const float* __restrict__ sc3, const float* __restrict__ sh3,
    const float* __restrict__ W4, const float* __restrict__ b4,
    float* __restrict__ out) {
  __shared__ Smem sm;
  const int blk = blockIdx.x;
  const int b  = blk >> 10;
  const int it = (blk >> 5) & 31;
  const int jt = blk & 31;
  const int i0 = it * 8, j0 = jt * 8;

  const int t    = threadIdx.x;
  const int w    = t >> 6;
  const int lane = t & 63;
  const int llo  = lane & 15;   // MFMA row/col within fragment
  const int lhi  = lane >> 4;   // MFMA k-group

  // ---- stage A'/B' tiles into LDS [row][k] f16, coalesced global reads ----
  {
    int ii = t >> 5;               // 0..7
    int c0 = (t & 31) * 16;        // 0..496
    const _Float16* aRowG = Ap + ((size_t)(b * 256 + i0 + ii) << 9) + c0;
    const _Float16* bRowG = Bp + ((size_t)(b * 256 + j0 + ii) << 9) + c0;
    f16x8 a0 = *(const f16x8*)aRowG;
    f16x8 a1 = *(const f16x8*)(aRowG + 8);
    f16x8 b0 = *(const f16x8*)bRowG;
    f16x8 b1 = *(const f16x8*)(bRowG + 8);
    *(f16x8*)&sm.u.s2.sA[ii][c0]     = a0;
    *(f16x8*)&sm.u.s2.sA[ii][c0 + 8] = a1;
    *(f16x8*)&sm.u.s2.sB[ii][c0]     = b0;
    *(f16x8*)&sm.u.s2.sB[ii][c0 + 8] = b1;
  }

  const f32x4 vzero = {0.f, 0.f, 0.f, 0.f};
  f32x4 acc[4][4];
  #pragma unroll
  for (int mt = 0; mt < 4; ++mt)
    #pragma unroll
    for (int nt = 0; nt < 4; ++nt) acc[mt][nt] = vzero;

  const int mbase = w * 64;
  const int gj    = llo & 7;     // j-row of this lane's point column
  const int giOff = llo >> 3;    // i-row parity within nt pair
  const _Float16* w2p = W2h + (size_t)(mbase + llo) * 512 + lhi * 8;

  // prime af for ks=0 (issues during staging-store latency)
  f16x8 af[4], afn[4];
  #pragma unroll
  for (int mt = 0; mt < 4; ++mt)
    af[mt] = *(const f16x8*)(w2p + (size_t)mt * 16 * 512);

  __syncthreads();   // staging complete; sA/sB read-only from here

  const f16x8 z8 = {};

  // ---- layer 2 K-loop: 16 steps of K=32, NO barriers ----
  for (int ks = 0; ks < 16; ++ks) {
    // prefetch next W2 fragments (consumed next iteration)
    if (ks < 15) {
      #pragma unroll
      for (int mt = 0; mt < 4; ++mt)
        afn[mt] = *(const f16x8*)(w2p + (size_t)mt * 16 * 512 + (ks + 1) * 32);
    }

    const int k0 = ks * 32 + lhi * 8;
    f16x8 bv = *(const f16x8*)&sm.u.s2.sB[gj][k0];

    f16x8 bfr[4];
    #pragma unroll
    for (int nt = 0; nt < 4; ++nt) {
      f16x8 av = *(const f16x8*)&sm.u.s2.sA[nt * 2 + giOff][k0];
      f16x8 s = av + bv;                           // v_pk_add_f16 x4
      bfr[nt] = __builtin_elementwise_max(s, z8);  // v_pk_max_f16 x4
    }

    #pragma unroll
    for (int mt = 0; mt < 4; ++mt)
      #pragma unroll
      for (int nt = 0; nt < 4; ++nt)
        acc[mt][nt] = __builtin_amdgcn_mfma_f32_16x16x32_f16(af[mt], bfr[nt], acc[mt][nt], 0, 0, 0);

    #pragma unroll
    for (int mt = 0; mt < 4; ++mt) af[mt] = afn[mt];
  }

  __syncthreads();   // all waves done reading sA/sB; union phase switch to h2

  // ---- BN2 + ReLU -> h2 (f16 in LDS) ----
  #pragma unroll
  for (int mt = 0; mt < 4; ++mt) {
    int ch = mbase + mt * 16 + lhi * 4;
    float4 s = *(const float4*)(sc2 + ch);
    float4 h = *(const float4*)(sh2 + ch);
    #pragma unroll
    for (int nt = 0; nt < 4; ++nt) {
      int pt = nt * 16 + llo;
      f16x4 hb;
      hb[0] = (_Float16)fmaxf(fmaf(acc[mt][nt][0], s.x, h.x), 0.f);
      hb[1] = (_Float16)fmaxf(fmaf(acc[mt][nt][1], s.y, h.y), 0.f);
      hb[2] = (_Float16)fmaxf(fmaf(acc[mt][nt][2], s.z, h.z), 0.f);
      hb[3] = (_Float16)fmaxf(fmaf(acc[mt][nt][3], s.w, h.w), 0.f);
      *(f16x4*)&sm.u.h2[pt][ch] = hb;          // 8B store, 8B-aligned
    }
  }
  __syncthreads();

  // ---- layer 3: wave w -> output channels [16w,16w+16) ----
  f32x4 acc3[4];
  #pragma unroll
  for (int nt = 0; nt < 4; ++nt) acc3[nt] = vzero;
  const _Float16* w3p = W3h + (size_t)(w * 16 + llo) * 256 + lhi * 8;
  #pragma unroll
  for (int ks = 0; ks < 8; ++ks) {
    f16x8 a3 = *(const f16x8*)(w3p + ks * 32);
    #pragma unroll
    for (int nt = 0; nt < 4; ++nt) {
      f16x8 b3 = *(const f16x8*)&sm.u.h2[nt * 16 + llo][ks * 32 + lhi * 8];
      acc3[nt] = __builtin_amdgcn_mfma_f32_16x16x32_f16(a3, b3, acc3[nt], 0, 0, 0);
    }
  }

  // ---- BN3 + ReLU + W4 dot folded in registers; cross-lane shfl reduce ----
  {
    int ch3 = w * 16 + lhi * 4;
    float4 s  = *(const float4*)(sc3 + ch3);
    float4 h  = *(const float4*)(sh3 + ch3);
    float4 wv = *(const float4*)(W4 + ch3);
    #pragma unroll
    for (int nt = 0; nt < 4; ++nt) {
      float p = fmaxf(fmaf(acc3[nt][0], s.x, h.x), 0.f) * wv.x
              + fmaxf(fmaf(acc3[nt][1], s.y, h.y), 0.f) * wv.y
              + fmaxf(fmaf(acc3[nt][2], s.z, h.z), 0.f) * wv.z
              + fmaxf(fmaf(acc3[nt][3], s.w, h.w), 0.f) * wv.w;
      p += __shfl_xor(p, 16);
      p += __shfl_xor(p, 32);
      if (lane < 16) sm.part[w][nt * 16 + llo] = p;   // lhi==0 lanes
    }
  }
  __syncthreads();

  // ---- cross-wave sum + sigmoid + store ----
  if (t < 64) {
    float tot = sm.part[0][t] + sm.part[1][t] + sm.part[2][t] + sm.part[3][t] + b4[0];
    float sg = 1.f / (1.f + __expf(-tot));
    out[(size_t)b * 65536 + (size_t)(i0 + (t >> 3)) * 256 + (j0 + (t & 7))] = sg;
  }
}

// ---------------- launcher ----------------
extern "C" void kernel_launch(void* const* d_in, const int* in_sizes, int n_in,
                              void* d_out, int out_size, void* d_ws, size_t ws_size,
                              hipStream_t stream) {
  const float* x   = (const float*)d_in[0];
  const float* W1  = (const float*)d_in[1];
  const float* b1  = (const float*)d_in[2];
  const float* g1  = (const float*)d_in[3];
  const float* be1 = (const float*)d_in[4];
  const float* m1  = (const float*)d_in[5];
  const float* v1  = (const float*)d_in[6];
  const float* W2  = (const float*)d_in[7];
  const float* b2  = (const float*)d_in[8];
  const float* g2  = (const float*)d_in[9];
  const float* be2 = (const float*)d_in[10];
  const float* m2  = (const float*)d_in[11];
  const float* v2  = (const float*)d_in[12];
  const float* W3  = (const float*)d_in[13];
  const float* b3  = (const float*)d_in[14];
  const float* g3  = (const float*)d_in[15];
  const float* be3 = (const float*)d_in[16];
  const float* m3  = (const float*)d_in[17];
  const float* v3  = (const float*)d_in[18];
  const float* W4  = (const float*)d_in[19];
  const float* b4  = (const float*)d_in[20];

  // workspace layout (~4.6 MB total)
  _Float16* Ap = (_Float16*)d_ws;        // 8*256*512 f16, [b][i][o]
  _Float16* Bp = Ap + 1048576;           // [b][j][o]
  float* sc1 = (float*)(Bp + 1048576);   // 512
  float* sh1 = sc1 + 512;                // 512
  float* sc2 = sh1 + 512;                // 256
  float* sh2 = sc2 + 256;                // 256
  float* sc3 = sh2 + 256;                // 64
  float* sh3 = sc3 + 64;                 // 64
  _Float16* W2h = (_Float16*)(sh3 + 64); // 131072 f16
  _Float16* W3h = W2h + 131072;          // 16384 f16

  prep_consts<<<1, 512, 0, stream>>>(b1, g1, be1, m1, v1, b2, g2, be2, m2, v2,
                                     b3, g3, be3, m3, v3, sc1, sh1, sc2, sh2, sc3, sh3);
  prep_convert<<<512, 256, 0, stream>>>(W2, W3, W2h, W3h);
  prep_ab<<<1024, 256, 0, stream>>>(x, W1, sc1, sh1, Ap, Bp);
  edge_main<<<8192, 256, 0, stream>>>(Ap, Bp, W2h, W3h, sc2, sh2, sc3, sh3, W4, b4, (float*)d_out);
}